// Round 12
// baseline (60.401 us; speedup 1.0000x reference)
//
#include <hip/hip_runtime.h>
#include <hip/hip_bf16.h>

constexpr int Bb  = 8;
constexpr int Nn  = 2048;
constexpr int FIN = 128;
constexpr int FOUT = 64;
constexpr float LOG2E = 1.4426950408889634f;

typedef __bf16 bf16x8 __attribute__((ext_vector_type(8)));
typedef __bf16 bf16x2 __attribute__((ext_vector_type(2)));
typedef float  f32x4  __attribute__((ext_vector_type(4)));
typedef int    i32x4  __attribute__((ext_vector_type(4)));
typedef unsigned int u32;
typedef unsigned long long u64;

__device__ __forceinline__ u32 f2bf_bits(float f) {
    u32 u = __builtin_bit_cast(u32, f);
    return (u + 0x7FFFu + ((u >> 16) & 1u)) >> 16;  // RNE
}

// Fused kernel 0+1 — identical to round 11 (dwordx4 bitpack verified there).
__global__ __launch_bounds__(256) void gat_k01(
        const float* __restrict__ h, const int* __restrict__ adj,
        const float* __restrict__ W, const float* __restrict__ a,
        __bf16* __restrict__ whfrag, float* __restrict__ fs,
        float* __restrict__ fd, u64* __restrict__ mask) {
    __shared__ __align__(16) float hT[32][FIN];   // 16 KB (k1 path only)

    const int l = threadIdx.x & 63;
    const int w = __builtin_amdgcn_readfirstlane((int)(threadIdx.x >> 6));

    if (blockIdx.x >= 512) {
        // ---- bitpack: 2048 blocks x 4 waves, 16 KB (4096 ints) per wave ----
        const size_t gw = (size_t)(blockIdx.x - 512) * 4 + w;   // 0..8191
        const int* p  = adj + gw * 4096 + 4 * l;                // 16 B/lane
        u64* mout     = mask + gw * 64;
        i32x4 vv[2];
        vv[0] = *reinterpret_cast<const i32x4*>(p);
#pragma unroll
        for (int i = 0; i < 16; ++i) {
            const int cur = i & 1;
            if (i < 15)
                vv[cur ^ 1] = *reinterpret_cast<const i32x4*>(p + (i + 1) * 256);
            const i32x4 v = vv[cur];
            u32 nib = (v[0] > 0 ? 1u : 0u) | (v[1] > 0 ? 2u : 0u) |
                      (v[2] > 0 ? 4u : 0u) | (v[3] > 0 ? 8u : 0u);
            u32 x = nib | (((u32)__shfl_xor((int)nib, 1)) << 4);
            x |= ((u32)__shfl_xor((int)x, 2)) << 8;
            x |= ((u32)__shfl_xor((int)x, 4)) << 16;
            u32 hi = (u32)__shfl_xor((int)x, 8);
            if ((l & 15) == 0)
                mout[i * 4 + (l >> 4)] = (u64)x | ((u64)hi << 32);
        }
        return;
    }

    // ---- k1 path: blocks 0..511 ----
    const int blk = blockIdx.x;
    const int b   = blk >> 6;
    const int t32 = blk & 63;
    const int n0  = t32 * 32;

    {
        const float4* hb = reinterpret_cast<const float4*>(h + (size_t)(b * Nn + n0) * FIN);
        float4* dst = reinterpret_cast<float4*>(&hT[0][0]);
#pragma unroll
        for (int k = 0; k < 4; ++k) {
            const int flat = threadIdx.x + k * 256;
            dst[flat] = hb[flat];
        }
    }
    __syncthreads();

    const float a0 = a[l];
    const float a1 = a[FOUT + l];

    float acc[8];
#pragma unroll
    for (int r = 0; r < 8; ++r) acc[r] = 0.f;

#pragma unroll 1
    for (int c0 = 0; c0 < FIN; c0 += 32) {
        float wreg[32];
#pragma unroll
        for (int cc = 0; cc < 32; ++cc) wreg[cc] = W[(c0 + cc) * FOUT + l];
#pragma unroll
        for (int r = 0; r < 8; ++r) {
            const int row = w * 8 + r;
#pragma unroll
            for (int cc = 0; cc < 32; ++cc)
                acc[r] = fmaf(hT[row][c0 + cc], wreg[cc], acc[r]);  // LDS broadcast
        }
    }

#pragma unroll
    for (int r = 0; r < 8; ++r) {
        float s0 = acc[r] * a0;
        float s1 = acc[r] * a1;
#pragma unroll
        for (int off = 32; off >= 1; off >>= 1) {
            s0 += __shfl_xor(s0, off, 64);
            s1 += __shfl_xor(s1, off, 64);
        }
        if (l == 0) {
            fs[b * Nn + n0 + w * 8 + r] = s0 * LOG2E;
            fd[b * Nn + n0 + w * 8 + r] = s1 * LOG2E;
        }
    }

    u32 pk[4];
#pragma unroll
    for (int i = 0; i < 4; ++i)
        pk[i] = f2bf_bits(acc[2 * i]) | (f2bf_bits(acc[2 * i + 1]) << 16);
    const int slotg = ((b * 64 + t32) * 4 + (l >> 4)) * 64 + ((w << 4) | (l & 15));
    reinterpret_cast<uint4*>(whfrag)[slotg] = make_uint4(pk[0], pk[1], pk[2], pk[3]);
}

// Kernel 2: REGISTER-DIRECT A-fragments — no LDS pipeline, no fences.
// Lane l builds A[row=l&15][k=(l>>4)*8 + 0..7] itself: fs of one row (held in
// a register), fd via two f32x4 broadcast loads, mask bits from its row's u64.
// Same math & rounding as r9 (bit-identical output). LDS only for the one-time
// combine epilogue. Geometry: 1024 blocks x 4 waves (wave = j-quarter).
__global__ __launch_bounds__(256, 4) void gat_k2(
        const u64* __restrict__ mask, const __bf16* __restrict__ whfrag,
        const float* __restrict__ fs, const float* __restrict__ fd,
        float* __restrict__ out) {
    const int blk = blockIdx.x;              // 1024 blocks
    const int b   = blk >> 7;
    const int i0  = (blk & 127) * 16;
    const int l   = threadIdx.x & 63;
    const int w   = __builtin_amdgcn_readfirstlane((int)(threadIdx.x >> 6)); // j quarter

    __shared__ f32x4 comb[4][4][64];                // 16 KB combine buffer
    __shared__ float zpart[4][16];

    const int row16 = l & 15;
    const int seg8  = (l >> 4) * 8;

    const float fsr = fs[b * Nn + i0 + row16];      // this lane's row, whole kernel

    const u64*   mrow = mask + ((size_t)b * Nn + i0 + row16) * 32 + w * 8;
    const float* fdq  = fd + b * Nn + w * 512 + seg8;

    const bf16x8* bfr = reinterpret_cast<const bf16x8*>(whfrag)
                        + (size_t)((b * 64 + w * 16) * 4) * 64 + l;

    f32x4 acc[4] = {{0,0,0,0},{0,0,0,0},{0,0,0,0},{0,0,0,0}};
    f32x4 accz   = {0.f, 0.f, 0.f, 0.f};

    bf16x8 onesv;
#pragma unroll
    for (int i = 0; i < 8; ++i) onesv[i] = (__bf16)1.0f;

#pragma unroll 2
    for (int jt = 0; jt < 8; ++jt) {
        const u64 mk = mrow[jt];                    // row's 64 mask bits for this tile
#pragma unroll
        for (int kb = 0; kb < 2; ++kb) {
            const f32x4 fd0 = *reinterpret_cast<const f32x4*>(fdq + jt * 64 + kb * 32);
            const f32x4 fd1 = *reinterpret_cast<const f32x4*>(fdq + jt * 64 + kb * 32 + 4);
            const u32 mb = (u32)(mk >> (kb * 32 + seg8)) & 0xffu;

            float pv[8];
#pragma unroll
            for (int r = 0; r < 4; ++r) {
                float e  = fsr + fd0[r];
                float lr = fmaxf(e, 0.2f * e);      // leaky relu (scale-safe)
                float p  = exp2f(lr);               // fs/fd pre-scaled by log2e
                pv[r] = ((mb >> r) & 1u) ? p : 0.f;
            }
#pragma unroll
            for (int r = 0; r < 4; ++r) {
                float e  = fsr + fd1[r];
                float lr = fmaxf(e, 0.2f * e);
                float p  = exp2f(lr);
                pv[4 + r] = ((mb >> (4 + r)) & 1u) ? p : 0.f;
            }

            uint4 pk4;
            pk4.x = __builtin_bit_cast(u32, (bf16x2){(__bf16)pv[0], (__bf16)pv[1]});
            pk4.y = __builtin_bit_cast(u32, (bf16x2){(__bf16)pv[2], (__bf16)pv[3]});
            pk4.z = __builtin_bit_cast(u32, (bf16x2){(__bf16)pv[4], (__bf16)pv[5]});
            pk4.w = __builtin_bit_cast(u32, (bf16x2){(__bf16)pv[6], (__bf16)pv[7]});
            const bf16x8 av = __builtin_bit_cast(bf16x8, pk4);

#pragma unroll
            for (int o16 = 0; o16 < 4; ++o16)
                acc[o16] = __builtin_amdgcn_mfma_f32_16x16x32_bf16(
                               av, bfr[((jt * 2 + kb) * 4 + o16) * 64], acc[o16], 0, 0, 0);
            accz = __builtin_amdgcn_mfma_f32_16x16x32_bf16(av, onesv, accz, 0, 0, 0);
        }
    }

    // Z partials: accz D-frag row=(l>>4)*4+r, col=l&15 (all cols identical)
    if ((l & 15) == 0) {
#pragma unroll
        for (int r = 0; r < 4; ++r) zpart[w][(l >> 4) * 4 + r] = accz[r];
    }
#pragma unroll
    for (int o16 = 0; o16 < 4; ++o16) comb[w][o16][l] = acc[o16];
    __syncthreads();

    // wave w finalizes output column block o16 = w
    f32x4 res = comb[0][w][l];
#pragma unroll
    for (int wp = 1; wp < 4; ++wp) res += comb[wp][w][l];

#pragma unroll
    for (int r = 0; r < 4; ++r) {
        const int row = (l >> 4) * 4 + r;              // C/D: row=(l>>4)*4+r, col=l&15
        float z = zpart[0][row] + zpart[1][row] + zpart[2][row] + zpart[3][row];
        float v = res[r] / z;
        v = v > 0.f ? v : expm1f(v);                   // ELU
        out[(size_t)(b * Nn + i0 + row) * FOUT + w * 16 + (l & 15)] = v;
    }
}

extern "C" void kernel_launch(void* const* d_in, const int* in_sizes, int n_in,
                              void* d_out, int out_size, void* d_ws, size_t ws_size,
                              hipStream_t stream) {
    const float* h   = (const float*)d_in[0];
    const int*   adj = (const int*)d_in[1];
    const float* W   = (const float*)d_in[2];
    const float* a   = (const float*)d_in[3];
    float* out = (float*)d_out;

    __bf16* whfrag = (__bf16*)d_ws;                                   // 2 MB
    float*  fs     = (float*)((char*)d_ws + (size_t)Bb * Nn * FOUT * 2);
    float*  fd     = fs + Bb * Nn;
    u64*    mask   = (u64*)((char*)d_ws + (4u << 20));                // 4 MB @ +4MB

    gat_k01<<<dim3(512 + 2048), dim3(256), 0, stream>>>(h, adj, W, a, whfrag, fs, fd, mask);
    gat_k2 <<<dim3(Bb * 128),   dim3(256), 0, stream>>>(mask, whfrag, fs, fd, out);
}